// Round 7
// baseline (518.845 us; speedup 1.0000x reference)
//
#include <hip/hip_runtime.h>
#include <hip/hip_bf16.h>
#include <stdint.h>

#define N_NODES 100000
#define N_EDGES 1200000
#define IN_CH 64
#define HID 16
#define OUT_CH 64

#define BN 100       // nodes per bucket (1000*100 == 100000 exactly)
#define NB 1000      // buckets
#define S1 21        // agg1 LDS row stride: 16 acc + 3 attr + 1 deg, odd pad
#define S2 17        // agg2 LDS row stride
#define SC_EPB 2048  // edges per scatter block

typedef __hip_bfloat16 bf16;

__device__ __forceinline__ float b2f(bf16 v) { return __bfloat162float(v); }
__device__ __forceinline__ float lo_f(uint32_t p) { return __uint_as_float(p << 16); }
__device__ __forceinline__ float hi_f(uint32_t p) { return __uint_as_float(p & 0xffff0000u); }

__device__ __forceinline__ float loadf(const void* p, size_t i, int bf) {
    return bf ? b2f(((const bf16*)p)[i]) : ((const float*)p)[i];
}
__device__ __forceinline__ uint32_t bfbits(const void* p, size_t i, int bf) {
    if (bf) return ((const uint16_t*)p)[i];
    float v = ((const float*)p)[i];
    bf16 h = __float2bfloat16(v);
    return *reinterpret_cast<uint16_t*>(&h);
}
// wide index loads: dst j, src j
__device__ __forceinline__ int ld_dst(const int* p, int j, int i64) {
    if (i64) return ((const int2*)p)[(size_t)N_EDGES + j].x;
    return p[(size_t)N_EDGES + j];
}
__device__ __forceinline__ int ld_src(const int* p, int j, int i64) {
    if (i64) return ((const int2*)p)[j].x;
    return p[j];
}

// Detect dtypes; fold layer-1 edge projection through W1l.
__global__ void k_prep(const void* __restrict__ x, const int* __restrict__ ei,
                       const void* __restrict__ W1e, const void* __restrict__ b1e,
                       const void* __restrict__ W1l, float* __restrict__ wc,
                       int* __restrict__ flags) {
    __shared__ int s_bf;
    if (threadIdx.x == 0) {
        const uint16_t* u = (const uint16_t*)x;
        int cnt = 0;
        for (int i = 0; i < 64; ++i) {
            int e = (u[i] >> 7) & 0xff;
            cnt += (e >= 100 && e <= 140);
        }
        int bf = (cnt >= 50);
        const uint32_t* w = (const uint32_t*)ei;
        int z = 0;
        for (int i = 1; i < 64; i += 2) z += (w[i] == 0u);
        flags[0] = bf;
        flags[1] = (z >= 16);
        s_bf = bf;
    }
    __syncthreads();
    int bf = s_bf;
    int j = threadIdx.x;
    if (j >= HID) return;
    for (int r = 0; r < 3; ++r) {
        float s = 0.f;
        for (int k = 0; k < IN_CH; ++k)
            s += loadf(W1e, r * IN_CH + k, bf) * loadf(W1l, k * HID + j, bf);
        wc[r * HID + j] = s;
    }
    float s = 0.f;
    for (int k = 0; k < IN_CH; ++k)
        s += loadf(b1e, k, bf) * loadf(W1l, k * HID + j, bf);
    wc[3 * HID + j] = s;
}

// y = x@W1l -> y (bf16); z = x@W1r + b1l + b1r -> zh (bf16). 32 threads/row.
__global__ void __launch_bounds__(256) k_y(const void* __restrict__ x,
                                           const void* __restrict__ W1l,
                                           const void* __restrict__ W1r,
                                           const void* __restrict__ b1l,
                                           const void* __restrict__ b1r,
                                           const int* __restrict__ flags,
                                           bf16* __restrict__ y,
                                           bf16* __restrict__ zh) {
    __shared__ float w[IN_CH * 32];
    __shared__ float bz[HID];
    int bf = flags[0];
    for (int t = threadIdx.x; t < IN_CH * 32; t += 256) {
        int k = t >> 5, cc = t & 31;
        w[t] = (cc < 16) ? loadf(W1l, k * HID + cc, bf) : loadf(W1r, k * HID + (cc - 16), bf);
    }
    if (threadIdx.x < HID)
        bz[threadIdx.x] = loadf(b1l, threadIdx.x, bf) + loadf(b1r, threadIdx.x, bf);
    __syncthreads();
    int tid = blockIdx.x * 256 + threadIdx.x;
    int row = tid >> 5;
    if (row >= N_NODES) return;
    int cc = tid & 31;
    float acc = 0.f;
    if (bf) {
        const uint32_t* xr = (const uint32_t*)x + (size_t)row * (IN_CH / 2);
#pragma unroll
        for (int k2 = 0; k2 < IN_CH / 2; ++k2) {
            uint32_t p = xr[k2];
            acc += lo_f(p) * w[(2 * k2) * 32 + cc] + hi_f(p) * w[(2 * k2 + 1) * 32 + cc];
        }
    } else {
        const float* xr = (const float*)x + (size_t)row * IN_CH;
#pragma unroll
        for (int k = 0; k < IN_CH; ++k) acc += xr[k] * w[k * 32 + cc];
    }
    if (cc < 16)
        y[(size_t)row * HID + cc] = __float2bfloat16(acc);
    else
        zh[(size_t)row * HID + (cc - 16)] = __float2bfloat16(acc + bz[cc - 16]);
}

// Bucket histogram (LDS-first, wide dst loads).
__global__ void __launch_bounds__(256) k_bhist(const int* __restrict__ ei,
                                               const int* __restrict__ flags,
                                               int* __restrict__ bcount) {
    __shared__ int lh[NB];
    for (int t = threadIdx.x; t < NB; t += 256) lh[t] = 0;
    __syncthreads();
    int i64 = flags[1];
    int stride = gridDim.x * 256;
    for (int e = blockIdx.x * 256 + threadIdx.x; e < N_EDGES; e += stride) {
        uint32_t dst = (uint32_t)ld_dst(ei, e, i64);
        atomicAdd(&lh[dst / BN], 1);
    }
    __syncthreads();
    for (int t = threadIdx.x; t < NB; t += 256)
        if (lh[t]) atomicAdd(&bcount[t], lh[t]);
}

// Exclusive scan of NB<=1024 bucket counts -> boff[0..NB], cursor copy.
__global__ void __launch_bounds__(1024) k_bscan(const int* __restrict__ bcount,
                                                int* __restrict__ boff,
                                                int* __restrict__ cursor) {
    __shared__ int s[1024];
    int t = threadIdx.x;
    int own = (t < NB) ? bcount[t] : 0;
    s[t] = own;
    __syncthreads();
    for (int off = 1; off < 1024; off <<= 1) {
        int v = (t >= off) ? s[t - off] : 0;
        __syncthreads();
        s[t] += v;
        __syncthreads();
    }
    if (t < NB) {
        int ex = s[t] - own;
        boff[t] = ex;
        cursor[t] = ex;
        if (t == NB - 1) boff[NB] = s[t];
    }
}

// Counting-sort scatter: slots[.] = {src | dl<<17, ea01}, ea2v[.] = ea2.
// rb pack: bucket<<20 | dl<<13 | rank  (bucket<1024, dl<128, rank<2048)
__global__ void __launch_bounds__(512) k_bscatter(const int* __restrict__ ei,
                                                  const void* __restrict__ ea,
                                                  const int* __restrict__ flags,
                                                  int* __restrict__ cursor,
                                                  uint2* __restrict__ slots,
                                                  uint16_t* __restrict__ ea2v) {
    __shared__ int lhist[NB];
    __shared__ int lbase[NB];
    for (int i = threadIdx.x; i < NB; i += 512) lhist[i] = 0;
    __syncthreads();
    int i64 = flags[1], bf = flags[0];
    int base = blockIdx.x * SC_EPB;
    uint32_t rb[4];
#pragma unroll
    for (int i = 0; i < 4; ++i) {
        int e = base + i * 512 + threadIdx.x;
        rb[i] = 0xFFFFFFFFu;
        if (e < N_EDGES) {
            uint32_t d = (uint32_t)ld_dst(ei, e, i64);
            uint32_t b = d / BN;
            uint32_t dl = d - b * BN;
            uint32_t r = (uint32_t)atomicAdd(&lhist[b], 1);
            rb[i] = (b << 20) | (dl << 13) | r;
        }
    }
    __syncthreads();
    for (int b = threadIdx.x; b < NB; b += 512)
        if (lhist[b]) lbase[b] = atomicAdd(&cursor[b], lhist[b]);
    __syncthreads();
#pragma unroll
    for (int i = 0; i < 4; ++i) {
        if (rb[i] == 0xFFFFFFFFu) continue;
        int e = base + i * 512 + threadIdx.x;
        uint32_t b = rb[i] >> 20;
        uint32_t dl = (rb[i] >> 13) & 0x7Fu;
        uint32_t r = rb[i] & 0x1FFFu;
        uint32_t s = (uint32_t)ld_src(ei, e, i64);
        uint32_t ea01 = bfbits(ea, (size_t)e * 3, bf) | (bfbits(ea, (size_t)e * 3 + 1, bf) << 16);
        size_t pos = (size_t)lbase[b] + r;
        slots[pos] = make_uint2(s | (dl << 17), ea01);
        ea2v[pos] = (uint16_t)bfbits(ea, (size_t)e * 3 + 2, bf);
    }
}

// Aggregation layer 1: one block per bucket, one LANE per edge, wide y-row loads,
// LDS ds_add_f32 accumulation (stride-21 rows). Epilogue: h = relu(mean+z) over zh.
__global__ void __launch_bounds__(256) k_agg1(const uint2* __restrict__ slots,
                                              const uint16_t* __restrict__ ea2v,
                                              const int* __restrict__ boff,
                                              const bf16* __restrict__ y,
                                              const float* __restrict__ wc,
                                              bf16* __restrict__ zh,
                                              float* __restrict__ sa,
                                              int* __restrict__ deg_i) {
    __shared__ float facc[BN * S1];  // 8.4 KB
    __shared__ float swc[64];
    int t = threadIdx.x;
    if (t < 64) swc[t] = wc[t];
    for (int i = t; i < BN * S1; i += 256) facc[i] = 0.f;
    __syncthreads();
    int b = blockIdx.x;
    int e0 = boff[b], n = boff[b + 1] - e0;
    const uint2* sp = slots + e0;
    const uint16_t* ep = ea2v + e0;
#define AGG1_EDGE(K)                                                                   \
    {                                                                                  \
        uint2 sl = sp[K];                                                              \
        uint32_t a2b = (uint32_t)ep[K];                                                \
        const uint4* yr = (const uint4*)(y + ((size_t)(sl.x & 0x1FFFFu)) * HID);       \
        uint4 p0 = yr[0], p1 = yr[1];                                                  \
        float* fb = &facc[(sl.x >> 17) * S1];                                          \
        atomicAdd(&fb[0], lo_f(p0.x));  atomicAdd(&fb[1], hi_f(p0.x));                 \
        atomicAdd(&fb[2], lo_f(p0.y));  atomicAdd(&fb[3], hi_f(p0.y));                 \
        atomicAdd(&fb[4], lo_f(p0.z));  atomicAdd(&fb[5], hi_f(p0.z));                 \
        atomicAdd(&fb[6], lo_f(p0.w));  atomicAdd(&fb[7], hi_f(p0.w));                 \
        atomicAdd(&fb[8], lo_f(p1.x));  atomicAdd(&fb[9], hi_f(p1.x));                 \
        atomicAdd(&fb[10], lo_f(p1.y)); atomicAdd(&fb[11], hi_f(p1.y));                \
        atomicAdd(&fb[12], lo_f(p1.z)); atomicAdd(&fb[13], hi_f(p1.z));                \
        atomicAdd(&fb[14], lo_f(p1.w)); atomicAdd(&fb[15], hi_f(p1.w));                \
        atomicAdd(&fb[16], lo_f(sl.y)); atomicAdd(&fb[17], hi_f(sl.y));                \
        atomicAdd(&fb[18], __uint_as_float(a2b << 16));                                \
        atomicAdd(&fb[19], 1.0f);                                                      \
    }
    int k = t;
    for (; k + 256 < n; k += 512) {
        AGG1_EDGE(k)
        AGG1_EDGE(k + 256)
    }
    if (k < n) AGG1_EDGE(k)
    __syncthreads();
    for (int idx = t; idx < BN * HID; idx += 256) {
        int dl = idx >> 4, cc = idx & 15;
        size_t i = (size_t)b * BN + dl;
        const float* fb = &facc[dl * S1];
        float d = fb[19];
        float inv = 1.0f / fmaxf(d, 1.0f);
        float a0 = fb[16], a1 = fb[17], a2 = fb[18];
        float tt = (fb[cc] + a0 * swc[cc] + a1 * swc[16 + cc] + a2 * swc[32 + cc] +
                    d * swc[48 + cc]) * inv;
        float h = fmaxf(tt + b2f(zh[i * HID + cc]), 0.0f);
        zh[i * HID + cc] = __float2bfloat16(h);
        if (cc < 3) sa[i * 3 + cc] = fb[16 + cc];
        else if (cc == 3) deg_i[i] = (int)d;
    }
}

// Aggregation layer 2 + output epilogue: one block per bucket, lane-per-edge.
__global__ void __launch_bounds__(256) k_agg2(const uint2* __restrict__ slots,
                                              const int* __restrict__ boff,
                                              const bf16* __restrict__ zh,  // holds h
                                              const float* __restrict__ sa,
                                              const int* __restrict__ deg_i,
                                              const void* __restrict__ W2l,
                                              const void* __restrict__ b2l,
                                              const void* __restrict__ W2r,
                                              const void* __restrict__ b2r,
                                              const void* __restrict__ W2e,
                                              const void* __restrict__ b2e,
                                              const int* __restrict__ flags,
                                              void* __restrict__ out) {
    __shared__ float facc[BN * S2];      // 6.8 KB
    __shared__ bf16  hl[BN * HID];       // 3.2 KB
    __shared__ float w2l[HID * OUT_CH];  // 4 KB
    __shared__ float w2r[HID * OUT_CH];  // 4 KB
    __shared__ float swe[3 * HID];
    __shared__ float sbe[HID];
    __shared__ float sbb[OUT_CH];
    int t = threadIdx.x;
    int bf = flags[0];
    for (int i = t; i < HID * OUT_CH; i += 256) {
        w2l[i] = loadf(W2l, i, bf);
        w2r[i] = loadf(W2r, i, bf);
    }
    if (t < 3 * HID) swe[t] = loadf(W2e, t, bf);
    if (t < HID) sbe[t] = loadf(b2e, t, bf);
    if (t < OUT_CH) sbb[t] = loadf(b2l, t, bf) + loadf(b2r, t, bf);
    for (int i = t; i < BN * S2; i += 256) facc[i] = 0.f;
    __syncthreads();
    int b = blockIdx.x;
    int e0 = boff[b], n = boff[b + 1] - e0;
    const uint2* sp = slots + e0;
#define AGG2_EDGE(K)                                                                   \
    {                                                                                  \
        uint2 sl = sp[K];                                                              \
        const uint4* hr = (const uint4*)(zh + ((size_t)(sl.x & 0x1FFFFu)) * HID);      \
        uint4 p0 = hr[0], p1 = hr[1];                                                  \
        float* fb = &facc[(sl.x >> 17) * S2];                                          \
        atomicAdd(&fb[0], lo_f(p0.x));  atomicAdd(&fb[1], hi_f(p0.x));                 \
        atomicAdd(&fb[2], lo_f(p0.y));  atomicAdd(&fb[3], hi_f(p0.y));                 \
        atomicAdd(&fb[4], lo_f(p0.z));  atomicAdd(&fb[5], hi_f(p0.z));                 \
        atomicAdd(&fb[6], lo_f(p0.w));  atomicAdd(&fb[7], hi_f(p0.w));                 \
        atomicAdd(&fb[8], lo_f(p1.x));  atomicAdd(&fb[9], hi_f(p1.x));                 \
        atomicAdd(&fb[10], lo_f(p1.y)); atomicAdd(&fb[11], hi_f(p1.y));                \
        atomicAdd(&fb[12], lo_f(p1.z)); atomicAdd(&fb[13], hi_f(p1.z));                \
        atomicAdd(&fb[14], lo_f(p1.w)); atomicAdd(&fb[15], hi_f(p1.w));                \
    }
    int k = t;
    for (; k + 256 < n; k += 512) {
        AGG2_EDGE(k)
        AGG2_EDGE(k + 256)
    }
    if (k < n) AGG2_EDGE(k)
    __syncthreads();
    // transform facc -> mean-path term; stage h locally
    for (int idx = t; idx < BN * HID; idx += 256) {
        int dl = idx >> 4, cc = idx & 15;
        size_t i = (size_t)b * BN + dl;
        float d = (float)deg_i[i];
        float inv = 1.0f / fmaxf(d, 1.0f);
        float a0 = sa[i * 3 + 0], a1 = sa[i * 3 + 1], a2 = sa[i * 3 + 2];
        facc[dl * S2 + cc] = (facc[dl * S2 + cc] + a0 * swe[cc] + a1 * swe[16 + cc] +
                              a2 * swe[32 + cc] + d * sbe[cc]) * inv;
        hl[idx] = zh[i * HID + cc];
    }
    __syncthreads();
    for (int idx = t; idx < BN * OUT_CH; idx += 256) {
        int dl = idx >> 6, j = idx & 63;
        size_t i = (size_t)b * BN + dl;
        float o = sbb[j];
#pragma unroll
        for (int cc = 0; cc < HID; ++cc)
            o += facc[dl * S2 + cc] * w2l[cc * OUT_CH + j] +
                 b2f(hl[dl * HID + cc]) * w2r[cc * OUT_CH + j];
        if (bf)
            ((bf16*)out)[i * OUT_CH + j] = __float2bfloat16(o);
        else
            ((float*)out)[i * OUT_CH + j] = o;
    }
}

extern "C" void kernel_launch(void* const* d_in, const int* in_sizes, int n_in,
                              void* d_out, int out_size, void* d_ws, size_t ws_size,
                              hipStream_t stream) {
    const void* x   = d_in[0];
    const int*  ei  = (const int*)d_in[1];
    const void* ea  = d_in[2];
    const void* W1l = d_in[3];
    const void* b1l = d_in[4];
    const void* W1r = d_in[5];
    const void* b1r = d_in[6];
    const void* W1e = d_in[7];
    const void* b1e = d_in[8];
    const void* W2l = d_in[9];
    const void* b2l = d_in[10];
    const void* W2r = d_in[11];
    const void* b2r = d_in[12];
    const void* W2e = d_in[13];
    const void* b2e = d_in[14];

    const size_t N16 = (size_t)N_NODES * HID;
    char* p = (char*)d_ws;
    uint2*    slots  = (uint2*)p;    p += (size_t)N_EDGES * sizeof(uint2);      // 9.6 MB
    uint16_t* ea2v   = (uint16_t*)p; p += (size_t)N_EDGES * sizeof(uint16_t);   // 2.4 MB
    bf16*     y      = (bf16*)p;     p += N16 * sizeof(bf16);                   // 3.2 MB
    bf16*     zh     = (bf16*)p;     p += N16 * sizeof(bf16);                   // 3.2 MB
    float*    sa     = (float*)p;    p += (size_t)3 * N_NODES * sizeof(float);  // 1.2 MB
    int*      deg_i  = (int*)p;      p += (size_t)N_NODES * sizeof(int);        // 0.4 MB
    int*      bcount = (int*)p;      p += NB * sizeof(int);
    int*      boff   = (int*)p;      p += (NB + 1) * sizeof(int);
    int*      cursor = (int*)p;      p += NB * sizeof(int);
    float*    wc     = (float*)p;    p += 64 * sizeof(float);
    int*      flags  = (int*)p;      p += 2 * sizeof(int);
    // total ~19.0 MiB

    hipMemsetAsync(bcount, 0, NB * sizeof(int), stream);

    k_prep<<<1, 64, 0, stream>>>(x, ei, W1e, b1e, W1l, wc, flags);
    k_y<<<((size_t)N_NODES * 32 + 255) / 256, 256, 0, stream>>>(x, W1l, W1r, b1l, b1r,
                                                                flags, y, zh);
    k_bhist<<<128, 256, 0, stream>>>(ei, flags, bcount);
    k_bscan<<<1, 1024, 0, stream>>>(bcount, boff, cursor);
    k_bscatter<<<(N_EDGES + SC_EPB - 1) / SC_EPB, 512, 0, stream>>>(ei, ea, flags, cursor,
                                                                    slots, ea2v);
    k_agg1<<<NB, 256, 0, stream>>>(slots, ea2v, boff, y, wc, zh, sa, deg_i);
    k_agg2<<<NB, 256, 0, stream>>>(slots, boff, zh, sa, deg_i, W2l, b2l, W2r, b2r,
                                   W2e, b2e, flags, d_out);
}

// Round 8
// 492.479 us; speedup vs baseline: 1.0535x; 1.0535x over previous
//
#include <hip/hip_runtime.h>
#include <hip/hip_bf16.h>
#include <stdint.h>

#define N_NODES 100000
#define N_EDGES 1200000
#define IN_CH 64
#define HID 16
#define OUT_CH 64

#define BN 100       // nodes per bucket (1000*100 == 100000 exactly)
#define NB 1000      // buckets
#define S1 21        // agg1 LDS row stride: 16 acc + 3 attr + 1 deg (odd pad)
#define S2 17        // agg2 LDS row stride
#define CAP 2048     // staged slots per bucket (Poisson(1200): never exceeded; tail handled)
#define SC_EPB 8192  // edges per scatter block

typedef __hip_bfloat16 bf16;

__device__ __forceinline__ float b2f(bf16 v) { return __bfloat162float(v); }
__device__ __forceinline__ float lo_f(uint32_t p) { return __uint_as_float(p << 16); }
__device__ __forceinline__ float hi_f(uint32_t p) { return __uint_as_float(p & 0xffff0000u); }

__device__ __forceinline__ float loadf(const void* p, size_t i, int bf) {
    return bf ? b2f(((const bf16*)p)[i]) : ((const float*)p)[i];
}
__device__ __forceinline__ uint32_t bfbits(const void* p, size_t i, int bf) {
    if (bf) return ((const uint16_t*)p)[i];
    float v = ((const float*)p)[i];
    bf16 h = __float2bfloat16(v);
    return *reinterpret_cast<uint16_t*>(&h);
}
__device__ __forceinline__ int ld_dst(const int* p, int j, int i64) {
    if (i64) return ((const int2*)p)[(size_t)N_EDGES + j].x;
    return p[(size_t)N_EDGES + j];
}
__device__ __forceinline__ int ld_src(const int* p, int j, int i64) {
    if (i64) return ((const int2*)p)[j].x;
    return p[j];
}

// Detect dtypes; fold layer-1 edge projection through W1l.
__global__ void k_prep(const void* __restrict__ x, const int* __restrict__ ei,
                       const void* __restrict__ W1e, const void* __restrict__ b1e,
                       const void* __restrict__ W1l, float* __restrict__ wc,
                       int* __restrict__ flags) {
    __shared__ int s_bf;
    if (threadIdx.x == 0) {
        const uint16_t* u = (const uint16_t*)x;
        int cnt = 0;
        for (int i = 0; i < 64; ++i) {
            int e = (u[i] >> 7) & 0xff;
            cnt += (e >= 100 && e <= 140);
        }
        int bf = (cnt >= 50);
        const uint32_t* w = (const uint32_t*)ei;
        int z = 0;
        for (int i = 1; i < 64; i += 2) z += (w[i] == 0u);
        flags[0] = bf;
        flags[1] = (z >= 16);
        s_bf = bf;
    }
    __syncthreads();
    int bf = s_bf;
    int j = threadIdx.x;
    if (j >= HID) return;
    for (int r = 0; r < 3; ++r) {
        float s = 0.f;
        for (int k = 0; k < IN_CH; ++k)
            s += loadf(W1e, r * IN_CH + k, bf) * loadf(W1l, k * HID + j, bf);
        wc[r * HID + j] = s;
    }
    float s = 0.f;
    for (int k = 0; k < IN_CH; ++k)
        s += loadf(b1e, k, bf) * loadf(W1l, k * HID + j, bf);
    wc[3 * HID + j] = s;
}

// y = x@W1l -> y (bf16); z = x@W1r + b1l + b1r -> zh (bf16). 32 threads/row.
__global__ void __launch_bounds__(256) k_y(const void* __restrict__ x,
                                           const void* __restrict__ W1l,
                                           const void* __restrict__ W1r,
                                           const void* __restrict__ b1l,
                                           const void* __restrict__ b1r,
                                           const int* __restrict__ flags,
                                           bf16* __restrict__ y,
                                           bf16* __restrict__ zh) {
    __shared__ float w[IN_CH * 32];
    __shared__ float bz[HID];
    int bf = flags[0];
    for (int t = threadIdx.x; t < IN_CH * 32; t += 256) {
        int k = t >> 5, cc = t & 31;
        w[t] = (cc < 16) ? loadf(W1l, k * HID + cc, bf) : loadf(W1r, k * HID + (cc - 16), bf);
    }
    if (threadIdx.x < HID)
        bz[threadIdx.x] = loadf(b1l, threadIdx.x, bf) + loadf(b1r, threadIdx.x, bf);
    __syncthreads();
    int tid = blockIdx.x * 256 + threadIdx.x;
    int row = tid >> 5;
    if (row >= N_NODES) return;
    int cc = tid & 31;
    float acc = 0.f;
    if (bf) {
        const uint32_t* xr = (const uint32_t*)x + (size_t)row * (IN_CH / 2);
#pragma unroll
        for (int k2 = 0; k2 < IN_CH / 2; ++k2) {
            uint32_t p = xr[k2];
            acc += lo_f(p) * w[(2 * k2) * 32 + cc] + hi_f(p) * w[(2 * k2 + 1) * 32 + cc];
        }
    } else {
        const float* xr = (const float*)x + (size_t)row * IN_CH;
#pragma unroll
        for (int k = 0; k < IN_CH; ++k) acc += xr[k] * w[k * 32 + cc];
    }
    if (cc < 16)
        y[(size_t)row * HID + cc] = __float2bfloat16(acc);
    else
        zh[(size_t)row * HID + (cc - 16)] = __float2bfloat16(acc + bz[cc - 16]);
}

// Bucket histogram (LDS-first).
__global__ void __launch_bounds__(256) k_bhist(const int* __restrict__ ei,
                                               const int* __restrict__ flags,
                                               int* __restrict__ bcount) {
    __shared__ int lh[NB];
    for (int t = threadIdx.x; t < NB; t += 256) lh[t] = 0;
    __syncthreads();
    int i64 = flags[1];
    int stride = gridDim.x * 256;
    for (int e = blockIdx.x * 256 + threadIdx.x; e < N_EDGES; e += stride) {
        uint32_t dst = (uint32_t)ld_dst(ei, e, i64);
        atomicAdd(&lh[dst / BN], 1);
    }
    __syncthreads();
    for (int t = threadIdx.x; t < NB; t += 256)
        if (lh[t]) atomicAdd(&bcount[t], lh[t]);
}

// Exclusive scan of NB<=1024 bucket counts -> boff[0..NB], cursor copy.
__global__ void __launch_bounds__(1024) k_bscan(const int* __restrict__ bcount,
                                                int* __restrict__ boff,
                                                int* __restrict__ cursor) {
    __shared__ int s[1024];
    int t = threadIdx.x;
    int own = (t < NB) ? bcount[t] : 0;
    s[t] = own;
    __syncthreads();
    for (int off = 1; off < 1024; off <<= 1) {
        int v = (t >= off) ? s[t - off] : 0;
        __syncthreads();
        s[t] += v;
        __syncthreads();
    }
    if (t < NB) {
        int ex = s[t] - own;
        boff[t] = ex;
        cursor[t] = ex;
        if (t == NB - 1) boff[NB] = s[t];
    }
}

// Counting-sort scatter: slots[.] = {src | dl<<17, ea01}, ea2v[.] = ea2.
// rb pack: bucket<<20 | dl<<13 | rank (bucket<1024, dl<128, rank<8192)
__global__ void __launch_bounds__(512) k_bscatter(const int* __restrict__ ei,
                                                  const void* __restrict__ ea,
                                                  const int* __restrict__ flags,
                                                  int* __restrict__ cursor,
                                                  uint2* __restrict__ slots,
                                                  uint16_t* __restrict__ ea2v) {
    __shared__ int lhist[NB];
    __shared__ int lbase[NB];
    for (int i = threadIdx.x; i < NB; i += 512) lhist[i] = 0;
    __syncthreads();
    int i64 = flags[1], bf = flags[0];
    int base = blockIdx.x * SC_EPB;
    uint32_t rb[16];
#pragma unroll
    for (int i = 0; i < 16; ++i) {
        int e = base + i * 512 + threadIdx.x;
        rb[i] = 0xFFFFFFFFu;
        if (e < N_EDGES) {
            uint32_t d = (uint32_t)ld_dst(ei, e, i64);
            uint32_t b = d / BN;
            uint32_t dl = d - b * BN;
            uint32_t r = (uint32_t)atomicAdd(&lhist[b], 1);
            rb[i] = (b << 20) | (dl << 13) | r;
        }
    }
    __syncthreads();
    for (int b = threadIdx.x; b < NB; b += 512)
        if (lhist[b]) lbase[b] = atomicAdd(&cursor[b], lhist[b]);
    __syncthreads();
#pragma unroll
    for (int i = 0; i < 16; ++i) {
        if (rb[i] == 0xFFFFFFFFu) continue;
        int e = base + i * 512 + threadIdx.x;
        uint32_t b = rb[i] >> 20;
        uint32_t dl = (rb[i] >> 13) & 0x7Fu;
        uint32_t r = rb[i] & 0x1FFFu;
        uint32_t s = (uint32_t)ld_src(ei, e, i64);
        uint32_t ea01 = bfbits(ea, (size_t)e * 3, bf) | (bfbits(ea, (size_t)e * 3 + 1, bf) << 16);
        size_t pos = (size_t)lbase[b] + r;
        slots[pos] = make_uint2(s | (dl << 17), ea01);
        ea2v[pos] = (uint16_t)bfbits(ea, (size_t)e * 3 + 2, bf);
    }
}

// Aggregation layer 1: one block per bucket. Work item = (edge, half-row):
// each lane loads 8 channels (uint4) of y[src]; 4 items batched for MLP;
// LDS-atomic accumulate. Epilogue: h = relu(mean+z) in place over zh.
__global__ void __launch_bounds__(256, 4) k_agg1(const uint2* __restrict__ slots,
                                                 const uint16_t* __restrict__ ea2v,
                                                 const int* __restrict__ boff,
                                                 const bf16* __restrict__ y,
                                                 const float* __restrict__ wc,
                                                 bf16* __restrict__ zh,
                                                 float* __restrict__ sa,
                                                 int* __restrict__ deg_i) {
    __shared__ uint2 su[CAP];        // 16 KB staged slots
    __shared__ float facc[BN * S1];  // 8.4 KB
    __shared__ float swc[64];
    int t = threadIdx.x;
    if (t < 64) swc[t] = wc[t];
    for (int i = t; i < BN * S1; i += 256) facc[i] = 0.f;
    int b = blockIdx.x;
    int e0 = boff[b], n = boff[b + 1] - e0;
    const uint2* sp = slots + e0;
    const uint16_t* ep = ea2v + e0;
    int nst = n < CAP ? n : CAP;
    for (int i = t; i < nst; i += 256) su[i] = sp[i];
    __syncthreads();

    uint32_t sx[4], sy_[4], e2[4];
    int hf[4];
    uint4 pr[4];
#define A1_LOAD(q, W)                                                              \
    {                                                                              \
        int k = (W) >> 1;                                                          \
        int half = (W) & 1;                                                        \
        uint2 sl = su[k];                                                          \
        sx[q] = sl.x; sy_[q] = sl.y; hf[q] = half;                                 \
        pr[q] = *(const uint4*)(y + ((size_t)(sl.x & 0x1FFFFu)) * HID + half * 8); \
        e2[q] = half ? 0u : (uint32_t)ep[k];                                       \
    }
#define A1_USE(q)                                                                  \
    {                                                                              \
        float* fb = &facc[(sx[q] >> 17) * S1];                                     \
        uint4 P = pr[q];                                                           \
        int bs = hf[q] * 8;                                                        \
        atomicAdd(&fb[bs + 0], lo_f(P.x)); atomicAdd(&fb[bs + 1], hi_f(P.x));      \
        atomicAdd(&fb[bs + 2], lo_f(P.y)); atomicAdd(&fb[bs + 3], hi_f(P.y));      \
        atomicAdd(&fb[bs + 4], lo_f(P.z)); atomicAdd(&fb[bs + 5], hi_f(P.z));      \
        atomicAdd(&fb[bs + 6], lo_f(P.w)); atomicAdd(&fb[bs + 7], hi_f(P.w));      \
        if (!hf[q]) {                                                              \
            atomicAdd(&fb[16], lo_f(sy_[q])); atomicAdd(&fb[17], hi_f(sy_[q]));    \
            atomicAdd(&fb[18], __uint_as_float(e2[q] << 16));                      \
            atomicAdd(&fb[19], 1.0f);                                              \
        }                                                                          \
    }
    int nw = 2 * nst;
    int w = t;
    for (; w + 768 < nw; w += 1024) {
        A1_LOAD(0, w) A1_LOAD(1, w + 256) A1_LOAD(2, w + 512) A1_LOAD(3, w + 768)
        A1_USE(0) A1_USE(1) A1_USE(2) A1_USE(3)
    }
    for (; w < nw; w += 256) { A1_LOAD(0, w) A1_USE(0) }
    // rare overflow tail (n > CAP): slots straight from global
    for (int w2 = 2 * CAP + t; w2 < 2 * n; w2 += 256) {
        int k = w2 >> 1;
        int half = w2 & 1;
        uint2 sl = sp[k];
        uint4 P = *(const uint4*)(y + ((size_t)(sl.x & 0x1FFFFu)) * HID + half * 8);
        float* fb = &facc[(sl.x >> 17) * S1];
        int bs = half * 8;
        atomicAdd(&fb[bs + 0], lo_f(P.x)); atomicAdd(&fb[bs + 1], hi_f(P.x));
        atomicAdd(&fb[bs + 2], lo_f(P.y)); atomicAdd(&fb[bs + 3], hi_f(P.y));
        atomicAdd(&fb[bs + 4], lo_f(P.z)); atomicAdd(&fb[bs + 5], hi_f(P.z));
        atomicAdd(&fb[bs + 6], lo_f(P.w)); atomicAdd(&fb[bs + 7], hi_f(P.w));
        if (!half) {
            atomicAdd(&fb[16], lo_f(sl.y)); atomicAdd(&fb[17], hi_f(sl.y));
            atomicAdd(&fb[18], __uint_as_float((uint32_t)ep[k] << 16));
            atomicAdd(&fb[19], 1.0f);
        }
    }
    __syncthreads();
    for (int idx = t; idx < BN * HID; idx += 256) {
        int dl = idx >> 4, cc = idx & 15;
        size_t i = (size_t)b * BN + dl;
        const float* fb = &facc[dl * S1];
        float d = fb[19];
        float inv = 1.0f / fmaxf(d, 1.0f);
        float a0 = fb[16], a1 = fb[17], a2 = fb[18];
        float tt = (fb[cc] + a0 * swc[cc] + a1 * swc[16 + cc] + a2 * swc[32 + cc] +
                    d * swc[48 + cc]) * inv;
        float h = fmaxf(tt + b2f(zh[i * HID + cc]), 0.0f);
        zh[i * HID + cc] = __float2bfloat16(h);
        if (cc < 3) sa[i * 3 + cc] = fb[16 + cc];
        else if (cc == 3) deg_i[i] = (int)d;
    }
}

// Aggregation layer 2 + output epilogue: one block per bucket, batched items.
__global__ void __launch_bounds__(256, 4) k_agg2(const uint2* __restrict__ slots,
                                                 const int* __restrict__ boff,
                                                 const bf16* __restrict__ zh,  // holds h
                                                 const float* __restrict__ sa,
                                                 const int* __restrict__ deg_i,
                                                 const void* __restrict__ W2l,
                                                 const void* __restrict__ b2l,
                                                 const void* __restrict__ W2r,
                                                 const void* __restrict__ b2r,
                                                 const void* __restrict__ W2e,
                                                 const void* __restrict__ b2e,
                                                 const int* __restrict__ flags,
                                                 void* __restrict__ out) {
    __shared__ uint2 su[CAP];            // 16 KB
    __shared__ float facc[BN * S2];      // 6.8 KB
    __shared__ bf16  hl[BN * HID];       // 3.2 KB
    __shared__ float w2l[HID * OUT_CH];  // 4 KB
    __shared__ float w2r[HID * OUT_CH];  // 4 KB
    __shared__ float swe[3 * HID];
    __shared__ float sbe[HID];
    __shared__ float sbb[OUT_CH];
    int t = threadIdx.x;
    int bf = flags[0];
    for (int i = t; i < HID * OUT_CH; i += 256) {
        w2l[i] = loadf(W2l, i, bf);
        w2r[i] = loadf(W2r, i, bf);
    }
    if (t < 3 * HID) swe[t] = loadf(W2e, t, bf);
    if (t < HID) sbe[t] = loadf(b2e, t, bf);
    if (t < OUT_CH) sbb[t] = loadf(b2l, t, bf) + loadf(b2r, t, bf);
    for (int i = t; i < BN * S2; i += 256) facc[i] = 0.f;
    int b = blockIdx.x;
    int e0 = boff[b], n = boff[b + 1] - e0;
    const uint2* sp = slots + e0;
    int nst = n < CAP ? n : CAP;
    for (int i = t; i < nst; i += 256) su[i] = sp[i];
    __syncthreads();

    uint32_t sx[4];
    int hf[4];
    uint4 pr[4];
#define A2_LOAD(q, W)                                                               \
    {                                                                               \
        int k = (W) >> 1;                                                           \
        int half = (W) & 1;                                                         \
        uint2 sl = su[k];                                                           \
        sx[q] = sl.x; hf[q] = half;                                                 \
        pr[q] = *(const uint4*)(zh + ((size_t)(sl.x & 0x1FFFFu)) * HID + half * 8); \
    }
#define A2_USE(q)                                                                   \
    {                                                                               \
        float* fb = &facc[(sx[q] >> 17) * S2 + hf[q] * 8];                          \
        uint4 P = pr[q];                                                            \
        atomicAdd(&fb[0], lo_f(P.x)); atomicAdd(&fb[1], hi_f(P.x));                 \
        atomicAdd(&fb[2], lo_f(P.y)); atomicAdd(&fb[3], hi_f(P.y));                 \
        atomicAdd(&fb[4], lo_f(P.z)); atomicAdd(&fb[5], hi_f(P.z));                 \
        atomicAdd(&fb[6], lo_f(P.w)); atomicAdd(&fb[7], hi_f(P.w));                 \
    }
    int nw = 2 * nst;
    int w = t;
    for (; w + 768 < nw; w += 1024) {
        A2_LOAD(0, w) A2_LOAD(1, w + 256) A2_LOAD(2, w + 512) A2_LOAD(3, w + 768)
        A2_USE(0) A2_USE(1) A2_USE(2) A2_USE(3)
    }
    for (; w < nw; w += 256) { A2_LOAD(0, w) A2_USE(0) }
    for (int w2 = 2 * CAP + t; w2 < 2 * n; w2 += 256) {
        int k = w2 >> 1;
        int half = w2 & 1;
        uint2 sl = sp[k];
        uint4 P = *(const uint4*)(zh + ((size_t)(sl.x & 0x1FFFFu)) * HID + half * 8);
        float* fb = &facc[(sl.x >> 17) * S2 + half * 8];
        atomicAdd(&fb[0], lo_f(P.x)); atomicAdd(&fb[1], hi_f(P.x));
        atomicAdd(&fb[2], lo_f(P.y)); atomicAdd(&fb[3], hi_f(P.y));
        atomicAdd(&fb[4], lo_f(P.z)); atomicAdd(&fb[5], hi_f(P.z));
        atomicAdd(&fb[6], lo_f(P.w)); atomicAdd(&fb[7], hi_f(P.w));
    }
    __syncthreads();
    for (int idx = t; idx < BN * HID; idx += 256) {
        int dl = idx >> 4, cc = idx & 15;
        size_t i = (size_t)b * BN + dl;
        float d = (float)deg_i[i];
        float inv = 1.0f / fmaxf(d, 1.0f);
        float a0 = sa[i * 3 + 0], a1 = sa[i * 3 + 1], a2 = sa[i * 3 + 2];
        facc[dl * S2 + cc] = (facc[dl * S2 + cc] + a0 * swe[cc] + a1 * swe[16 + cc] +
                              a2 * swe[32 + cc] + d * sbe[cc]) * inv;
        hl[idx] = zh[i * HID + cc];
    }
    __syncthreads();
    for (int idx = t; idx < BN * OUT_CH; idx += 256) {
        int dl = idx >> 6, j = idx & 63;
        size_t i = (size_t)b * BN + dl;
        float o = sbb[j];
#pragma unroll
        for (int cc = 0; cc < HID; ++cc)
            o += facc[dl * S2 + cc] * w2l[cc * OUT_CH + j] +
                 b2f(hl[dl * HID + cc]) * w2r[cc * OUT_CH + j];
        if (bf)
            ((bf16*)out)[i * OUT_CH + j] = __float2bfloat16(o);
        else
            ((float*)out)[i * OUT_CH + j] = o;
    }
}

extern "C" void kernel_launch(void* const* d_in, const int* in_sizes, int n_in,
                              void* d_out, int out_size, void* d_ws, size_t ws_size,
                              hipStream_t stream) {
    const void* x   = d_in[0];
    const int*  ei  = (const int*)d_in[1];
    const void* ea  = d_in[2];
    const void* W1l = d_in[3];
    const void* b1l = d_in[4];
    const void* W1r = d_in[5];
    const void* b1r = d_in[6];
    const void* W1e = d_in[7];
    const void* b1e = d_in[8];
    const void* W2l = d_in[9];
    const void* b2l = d_in[10];
    const void* W2r = d_in[11];
    const void* b2r = d_in[12];
    const void* W2e = d_in[13];
    const void* b2e = d_in[14];

    const size_t N16 = (size_t)N_NODES * HID;
    char* p = (char*)d_ws;
    uint2*    slots  = (uint2*)p;    p += (size_t)N_EDGES * sizeof(uint2);      // 9.6 MB
    uint16_t* ea2v   = (uint16_t*)p; p += (size_t)N_EDGES * sizeof(uint16_t);   // 2.4 MB
    bf16*     y      = (bf16*)p;     p += N16 * sizeof(bf16);                   // 3.2 MB
    bf16*     zh     = (bf16*)p;     p += N16 * sizeof(bf16);                   // 3.2 MB
    float*    sa     = (float*)p;    p += (size_t)3 * N_NODES * sizeof(float);  // 1.2 MB
    int*      deg_i  = (int*)p;      p += (size_t)N_NODES * sizeof(int);        // 0.4 MB
    int*      bcount = (int*)p;      p += NB * sizeof(int);
    int*      boff   = (int*)p;      p += (NB + 1) * sizeof(int);
    int*      cursor = (int*)p;      p += NB * sizeof(int);
    float*    wc     = (float*)p;    p += 64 * sizeof(float);
    int*      flags  = (int*)p;      p += 2 * sizeof(int);
    // total ~19.0 MiB

    hipMemsetAsync(bcount, 0, NB * sizeof(int), stream);

    k_prep<<<1, 64, 0, stream>>>(x, ei, W1e, b1e, W1l, wc, flags);
    k_y<<<((size_t)N_NODES * 32 + 255) / 256, 256, 0, stream>>>(x, W1l, W1r, b1l, b1r,
                                                                flags, y, zh);
    k_bhist<<<128, 256, 0, stream>>>(ei, flags, bcount);
    k_bscan<<<1, 1024, 0, stream>>>(bcount, boff, cursor);
    k_bscatter<<<(N_EDGES + SC_EPB - 1) / SC_EPB, 512, 0, stream>>>(ei, ea, flags, cursor,
                                                                    slots, ea2v);
    k_agg1<<<NB, 256, 0, stream>>>(slots, ea2v, boff, y, wc, zh, sa, deg_i);
    k_agg2<<<NB, 256, 0, stream>>>(slots, boff, zh, sa, deg_i, W2l, b2l, W2r, b2r,
                                   W2e, b2e, flags, d_out);
}

// Round 9
// 278.800 us; speedup vs baseline: 1.8610x; 1.7664x over previous
//
#include <hip/hip_runtime.h>
#include <hip/hip_bf16.h>
#include <stdint.h>

#define N_NODES 100000
#define N_EDGES 1200000
#define IN_CH 64
#define HID 16
#define OUT_CH 64

#define BN 100       // nodes per bucket (1000*100 == 100000 exactly)
#define NB 1000      // buckets
#define CAP 2048     // staged slots per chunk (bucket ~Poisson(1200); chunk loop handles any n)
#define SC_EPB 8192  // edges per scatter block

typedef __hip_bfloat16 bf16;

__device__ __forceinline__ float b2f(bf16 v) { return __bfloat162float(v); }
__device__ __forceinline__ float lo_f(uint32_t p) { return __uint_as_float(p << 16); }
__device__ __forceinline__ float hi_f(uint32_t p) { return __uint_as_float(p & 0xffff0000u); }
__device__ __forceinline__ uint16_t f2bb(float v) {
    bf16 h = __float2bfloat16(v);
    return *reinterpret_cast<uint16_t*>(&h);
}

__device__ __forceinline__ float loadf(const void* p, size_t i, int bf) {
    return bf ? b2f(((const bf16*)p)[i]) : ((const float*)p)[i];
}
__device__ __forceinline__ uint32_t bfbits(const void* p, size_t i, int bf) {
    if (bf) return ((const uint16_t*)p)[i];
    return f2bb(((const float*)p)[i]);
}
__device__ __forceinline__ int ld_dst(const int* p, int j, int i64) {
    if (i64) return ((const int2*)p)[(size_t)N_EDGES + j].x;
    return p[(size_t)N_EDGES + j];
}
__device__ __forceinline__ int ld_src(const int* p, int j, int i64) {
    if (i64) return ((const int2*)p)[j].x;
    return p[j];
}

// Detect dtypes; fold layer-1 edge projection through W1l.
__global__ void k_prep(const void* __restrict__ x, const int* __restrict__ ei,
                       const void* __restrict__ W1e, const void* __restrict__ b1e,
                       const void* __restrict__ W1l, float* __restrict__ wc,
                       int* __restrict__ flags) {
    __shared__ int s_bf;
    if (threadIdx.x == 0) {
        const uint16_t* u = (const uint16_t*)x;
        int cnt = 0;
        for (int i = 0; i < 64; ++i) {
            int e = (u[i] >> 7) & 0xff;
            cnt += (e >= 100 && e <= 140);
        }
        int bf = (cnt >= 50);
        const uint32_t* w = (const uint32_t*)ei;
        int z = 0;
        for (int i = 1; i < 64; i += 2) z += (w[i] == 0u);
        flags[0] = bf;
        flags[1] = (z >= 16);
        s_bf = bf;
    }
    __syncthreads();
    int bf = s_bf;
    int j = threadIdx.x;
    if (j >= HID) return;
    for (int r = 0; r < 3; ++r) {
        float s = 0.f;
        for (int k = 0; k < IN_CH; ++k)
            s += loadf(W1e, r * IN_CH + k, bf) * loadf(W1l, k * HID + j, bf);
        wc[r * HID + j] = s;
    }
    float s = 0.f;
    for (int k = 0; k < IN_CH; ++k)
        s += loadf(b1e, k, bf) * loadf(W1l, k * HID + j, bf);
    wc[3 * HID + j] = s;
}

// y = x@W1l -> y (bf16); z = x@W1r + b1l + b1r -> zh (bf16). 32 threads/row.
__global__ void __launch_bounds__(256) k_y(const void* __restrict__ x,
                                           const void* __restrict__ W1l,
                                           const void* __restrict__ W1r,
                                           const void* __restrict__ b1l,
                                           const void* __restrict__ b1r,
                                           const int* __restrict__ flags,
                                           bf16* __restrict__ y,
                                           bf16* __restrict__ zh) {
    __shared__ float w[IN_CH * 32];
    __shared__ float bz[HID];
    int bf = flags[0];
    for (int t = threadIdx.x; t < IN_CH * 32; t += 256) {
        int k = t >> 5, cc = t & 31;
        w[t] = (cc < 16) ? loadf(W1l, k * HID + cc, bf) : loadf(W1r, k * HID + (cc - 16), bf);
    }
    if (threadIdx.x < HID)
        bz[threadIdx.x] = loadf(b1l, threadIdx.x, bf) + loadf(b1r, threadIdx.x, bf);
    __syncthreads();
    int tid = blockIdx.x * 256 + threadIdx.x;
    int row = tid >> 5;
    if (row >= N_NODES) return;
    int cc = tid & 31;
    float acc = 0.f;
    if (bf) {
        const uint32_t* xr = (const uint32_t*)x + (size_t)row * (IN_CH / 2);
#pragma unroll
        for (int k2 = 0; k2 < IN_CH / 2; ++k2) {
            uint32_t p = xr[k2];
            acc += lo_f(p) * w[(2 * k2) * 32 + cc] + hi_f(p) * w[(2 * k2 + 1) * 32 + cc];
        }
    } else {
        const float* xr = (const float*)x + (size_t)row * IN_CH;
#pragma unroll
        for (int k = 0; k < IN_CH; ++k) acc += xr[k] * w[k * 32 + cc];
    }
    if (cc < 16)
        y[(size_t)row * HID + cc] = __float2bfloat16(acc);
    else
        zh[(size_t)row * HID + (cc - 16)] = __float2bfloat16(acc + bz[cc - 16]);
}

// Bucket histogram (LDS-first).
__global__ void __launch_bounds__(256) k_bhist(const int* __restrict__ ei,
                                               const int* __restrict__ flags,
                                               int* __restrict__ bcount) {
    __shared__ int lh[NB];
    for (int t = threadIdx.x; t < NB; t += 256) lh[t] = 0;
    __syncthreads();
    int i64 = flags[1];
    int stride = gridDim.x * 256;
    for (int e = blockIdx.x * 256 + threadIdx.x; e < N_EDGES; e += stride) {
        uint32_t dst = (uint32_t)ld_dst(ei, e, i64);
        atomicAdd(&lh[dst / BN], 1);
    }
    __syncthreads();
    for (int t = threadIdx.x; t < NB; t += 256)
        if (lh[t]) atomicAdd(&bcount[t], lh[t]);
}

// Exclusive scan of NB<=1024 bucket counts -> boff[0..NB], cursor copy.
__global__ void __launch_bounds__(1024) k_bscan(const int* __restrict__ bcount,
                                                int* __restrict__ boff,
                                                int* __restrict__ cursor) {
    __shared__ int s[1024];
    int t = threadIdx.x;
    int own = (t < NB) ? bcount[t] : 0;
    s[t] = own;
    __syncthreads();
    for (int off = 1; off < 1024; off <<= 1) {
        int v = (t >= off) ? s[t - off] : 0;
        __syncthreads();
        s[t] += v;
        __syncthreads();
    }
    if (t < NB) {
        int ex = s[t] - own;
        boff[t] = ex;
        cursor[t] = ex;
        if (t == NB - 1) boff[NB] = s[t];
    }
}

// Counting-sort scatter: slots[.] = {src | dl<<17, ea01}, ea2v[.] = ea2.
__global__ void __launch_bounds__(512) k_bscatter(const int* __restrict__ ei,
                                                  const void* __restrict__ ea,
                                                  const int* __restrict__ flags,
                                                  int* __restrict__ cursor,
                                                  uint2* __restrict__ slots,
                                                  uint16_t* __restrict__ ea2v) {
    __shared__ int lhist[NB];
    __shared__ int lbase[NB];
    for (int i = threadIdx.x; i < NB; i += 512) lhist[i] = 0;
    __syncthreads();
    int i64 = flags[1], bf = flags[0];
    int base = blockIdx.x * SC_EPB;
    uint32_t rb[16];
#pragma unroll
    for (int i = 0; i < 16; ++i) {
        int e = base + i * 512 + threadIdx.x;
        rb[i] = 0xFFFFFFFFu;
        if (e < N_EDGES) {
            uint32_t d = (uint32_t)ld_dst(ei, e, i64);
            uint32_t b = d / BN;
            uint32_t dl = d - b * BN;
            uint32_t r = (uint32_t)atomicAdd(&lhist[b], 1);
            rb[i] = (b << 20) | (dl << 13) | r;
        }
    }
    __syncthreads();
    for (int b = threadIdx.x; b < NB; b += 512)
        if (lhist[b]) lbase[b] = atomicAdd(&cursor[b], lhist[b]);
    __syncthreads();
#pragma unroll
    for (int i = 0; i < 16; ++i) {
        if (rb[i] == 0xFFFFFFFFu) continue;
        int e = base + i * 512 + threadIdx.x;
        uint32_t b = rb[i] >> 20;
        uint32_t dl = (rb[i] >> 13) & 0x7Fu;
        uint32_t r = rb[i] & 0x1FFFu;
        uint32_t s = (uint32_t)ld_src(ei, e, i64);
        uint32_t ea01 = bfbits(ea, (size_t)e * 3, bf) | (bfbits(ea, (size_t)e * 3 + 1, bf) << 16);
        size_t pos = (size_t)lbase[b] + r;
        slots[pos] = make_uint2(s | (dl << 17), ea01);
        ea2v[pos] = (uint16_t)bfbits(ea, (size_t)e * 3 + 2, bf);
    }
}

// ---- shared within-bucket counting sort (by dl) machinery --------------------
// After SORT_CHUNK: sidx[noff[dl]..] lists staged-slot indices of node dl.
#define SORT_CHUNK(nst)                                                        \
    {                                                                          \
        for (int i_ = t; i_ < (nst); i_ += 256)                                \
            atomicAdd(&hist[su[i_].x >> 17], 1);                               \
        __syncthreads();                                                       \
        if (t < 128) sbuf[t] = (t < BN) ? hist[t] : 0;                         \
        __syncthreads();                                                       \
        for (int off_ = 1; off_ < 128; off_ <<= 1) {                           \
            int v_ = 0;                                                        \
            if (t < 128 && t >= off_) v_ = sbuf[t - off_];                     \
            __syncthreads();                                                   \
            if (t < 128) sbuf[t] += v_;                                        \
            __syncthreads();                                                   \
        }                                                                      \
        if (t < BN) {                                                          \
            int ex_ = sbuf[t] - hist[t];                                       \
            noff[t] = ex_;                                                     \
            cur[t] = ex_;                                                      \
        }                                                                      \
        __syncthreads();                                                       \
        for (int i_ = t; i_ < (nst); i_ += 256) {                              \
            int r_ = atomicAdd(&cur[su[i_].x >> 17], 1);                       \
            sidx[r_] = (uint16_t)i_;                                           \
        }                                                                      \
        __syncthreads();                                                       \
    }

// Aggregation layer 1: one block per bucket; within-bucket sort by dl; 2 lanes
// per node register-accumulate y[src] (+attr, deg); epilogue h=relu(mean+z).
__global__ void __launch_bounds__(256) k_agg1(const uint2* __restrict__ slots,
                                              const uint16_t* __restrict__ ea2v,
                                              const int* __restrict__ boff,
                                              const bf16* __restrict__ y,
                                              const float* __restrict__ wc,
                                              bf16* __restrict__ zh,
                                              float* __restrict__ sa) {
    __shared__ uint2 su[CAP];        // 16 KB
    __shared__ uint16_t ea2s[CAP];   // 4 KB
    __shared__ uint16_t sidx[CAP];   // 4 KB
    __shared__ int hist[BN], noff[BN], cur[BN], sbuf[128];
    __shared__ float swc[64];
    int t = threadIdx.x;
    if (t < 64) swc[t] = wc[t];
    int b = blockIdx.x;
    int e0 = boff[b], n = boff[b + 1] - e0;
    const uint2* sp = slots + e0;
    const uint16_t* ep = ea2v + e0;
    int dl = t >> 1, half = t & 1, cs = half * 8;
    float acc[8] = {0.f, 0.f, 0.f, 0.f, 0.f, 0.f, 0.f, 0.f};
    float a0 = 0.f, a1 = 0.f, a2 = 0.f, degT = 0.f;

    for (int base = 0; base < n; base += CAP) {
        int nst = n - base < CAP ? n - base : CAP;
        for (int i_ = t; i_ < BN; i_ += 256) hist[i_] = 0;
        for (int i_ = t; i_ < nst; i_ += 256) {
            su[i_] = sp[base + i_];
            ea2s[i_] = ep[base + i_];
        }
        __syncthreads();
        SORT_CHUNK(nst)
        if (dl < BN) {
            int kb = noff[dl];
            int ke = (dl == BN - 1) ? nst : noff[dl + 1];
            int k = kb;
            for (; k + 3 < ke; k += 4) {
                int i0 = sidx[k], i1 = sidx[k + 1], i2 = sidx[k + 2], i3 = sidx[k + 3];
                uint2 s0 = su[i0], s1 = su[i1], s2 = su[i2], s3 = su[i3];
                uint4 q0 = *(const uint4*)(y + (size_t)(s0.x & 0x1FFFFu) * HID + cs);
                uint4 q1 = *(const uint4*)(y + (size_t)(s1.x & 0x1FFFFu) * HID + cs);
                uint4 q2 = *(const uint4*)(y + (size_t)(s2.x & 0x1FFFFu) * HID + cs);
                uint4 q3 = *(const uint4*)(y + (size_t)(s3.x & 0x1FFFFu) * HID + cs);
                acc[0] += lo_f(q0.x) + lo_f(q1.x) + lo_f(q2.x) + lo_f(q3.x);
                acc[1] += hi_f(q0.x) + hi_f(q1.x) + hi_f(q2.x) + hi_f(q3.x);
                acc[2] += lo_f(q0.y) + lo_f(q1.y) + lo_f(q2.y) + lo_f(q3.y);
                acc[3] += hi_f(q0.y) + hi_f(q1.y) + hi_f(q2.y) + hi_f(q3.y);
                acc[4] += lo_f(q0.z) + lo_f(q1.z) + lo_f(q2.z) + lo_f(q3.z);
                acc[5] += hi_f(q0.z) + hi_f(q1.z) + hi_f(q2.z) + hi_f(q3.z);
                acc[6] += lo_f(q0.w) + lo_f(q1.w) + lo_f(q2.w) + lo_f(q3.w);
                acc[7] += hi_f(q0.w) + hi_f(q1.w) + hi_f(q2.w) + hi_f(q3.w);
                if (half == 0) {
                    a0 += lo_f(s0.y) + lo_f(s1.y) + lo_f(s2.y) + lo_f(s3.y);
                    a1 += hi_f(s0.y) + hi_f(s1.y) + hi_f(s2.y) + hi_f(s3.y);
                    a2 += __uint_as_float((uint32_t)ea2s[i0] << 16) +
                          __uint_as_float((uint32_t)ea2s[i1] << 16) +
                          __uint_as_float((uint32_t)ea2s[i2] << 16) +
                          __uint_as_float((uint32_t)ea2s[i3] << 16);
                }
            }
            for (; k < ke; ++k) {
                int i0 = sidx[k];
                uint2 s0 = su[i0];
                uint4 q0 = *(const uint4*)(y + (size_t)(s0.x & 0x1FFFFu) * HID + cs);
                acc[0] += lo_f(q0.x); acc[1] += hi_f(q0.x);
                acc[2] += lo_f(q0.y); acc[3] += hi_f(q0.y);
                acc[4] += lo_f(q0.z); acc[5] += hi_f(q0.z);
                acc[6] += lo_f(q0.w); acc[7] += hi_f(q0.w);
                if (half == 0) {
                    a0 += lo_f(s0.y);
                    a1 += hi_f(s0.y);
                    a2 += __uint_as_float((uint32_t)ea2s[i0] << 16);
                }
            }
            degT += (float)hist[dl];
        }
        __syncthreads();
    }
    // epilogue (registers only)
    if (dl < BN) {
        a0 += __shfl_xor(a0, 1);  // pair lanes (2dl, 2dl+1): one side held zeros
        a1 += __shfl_xor(a1, 1);
        a2 += __shfl_xor(a2, 1);
        size_t i = (size_t)b * BN + dl;
        float inv = 1.0f / fmaxf(degT, 1.0f);
        uint4 zq = *(const uint4*)(zh + i * HID + cs);
        float zf[8] = {lo_f(zq.x), hi_f(zq.x), lo_f(zq.y), hi_f(zq.y),
                       lo_f(zq.z), hi_f(zq.z), lo_f(zq.w), hi_f(zq.w)};
        uint32_t pk[4];
#pragma unroll
        for (int j = 0; j < 4; ++j) {
            float t0 = (acc[2 * j] + a0 * swc[cs + 2 * j] + a1 * swc[16 + cs + 2 * j] +
                        a2 * swc[32 + cs + 2 * j] + degT * swc[48 + cs + 2 * j]) * inv;
            float t1 = (acc[2 * j + 1] + a0 * swc[cs + 2 * j + 1] + a1 * swc[17 + cs + 2 * j] +
                        a2 * swc[33 + cs + 2 * j] + degT * swc[49 + cs + 2 * j]) * inv;
            float h0 = fmaxf(t0 + zf[2 * j], 0.f);
            float h1 = fmaxf(t1 + zf[2 * j + 1], 0.f);
            pk[j] = (uint32_t)f2bb(h0) | ((uint32_t)f2bb(h1) << 16);
        }
        *(uint4*)(zh + i * HID + cs) = make_uint4(pk[0], pk[1], pk[2], pk[3]);
        if (half == 0) {
            sa[i * 3 + 0] = a0;
            sa[i * 3 + 1] = a1;
            sa[i * 3 + 2] = a2;
        }
    }
}

// Aggregation layer 2 + output epilogue: sort, register-accumulate h, matmul.
__global__ void __launch_bounds__(256) k_agg2(const uint2* __restrict__ slots,
                                              const int* __restrict__ boff,
                                              const bf16* __restrict__ zh,  // holds h
                                              const float* __restrict__ sa,
                                              const void* __restrict__ W2l,
                                              const void* __restrict__ b2l,
                                              const void* __restrict__ W2r,
                                              const void* __restrict__ b2r,
                                              const void* __restrict__ W2e,
                                              const void* __restrict__ b2e,
                                              const int* __restrict__ flags,
                                              void* __restrict__ out) {
    __shared__ uint2 su[CAP];        // 16 KB
    __shared__ uint16_t sidx[CAP];   // 4 KB
    __shared__ int hist[BN], noff[BN], cur[BN], sbuf[128];
    __shared__ float facc[BN * HID];     // 6.4 KB
    __shared__ bf16 hl[BN * HID];        // 3.2 KB
    __shared__ float w2l[HID * OUT_CH];  // 4 KB
    __shared__ float w2r[HID * OUT_CH];  // 4 KB
    __shared__ float swe[3 * HID];
    __shared__ float sbe[HID];
    __shared__ float sbb[OUT_CH];
    int t = threadIdx.x;
    int bf = flags[0];
    for (int i = t; i < HID * OUT_CH; i += 256) {
        w2l[i] = loadf(W2l, i, bf);
        w2r[i] = loadf(W2r, i, bf);
    }
    if (t < 3 * HID) swe[t] = loadf(W2e, t, bf);
    if (t < HID) sbe[t] = loadf(b2e, t, bf);
    if (t < OUT_CH) sbb[t] = loadf(b2l, t, bf) + loadf(b2r, t, bf);
    int b = blockIdx.x;
    int e0 = boff[b], n = boff[b + 1] - e0;
    const uint2* sp = slots + e0;
    int dl = t >> 1, half = t & 1, cs = half * 8;
    float acc[8] = {0.f, 0.f, 0.f, 0.f, 0.f, 0.f, 0.f, 0.f};
    float degT = 0.f;

    for (int base = 0; base < n; base += CAP) {
        int nst = n - base < CAP ? n - base : CAP;
        for (int i_ = t; i_ < BN; i_ += 256) hist[i_] = 0;
        for (int i_ = t; i_ < nst; i_ += 256) su[i_] = sp[base + i_];
        __syncthreads();
        SORT_CHUNK(nst)
        if (dl < BN) {
            int kb = noff[dl];
            int ke = (dl == BN - 1) ? nst : noff[dl + 1];
            int k = kb;
            for (; k + 3 < ke; k += 4) {
                int i0 = sidx[k], i1 = sidx[k + 1], i2 = sidx[k + 2], i3 = sidx[k + 3];
                uint2 s0 = su[i0], s1 = su[i1], s2 = su[i2], s3 = su[i3];
                uint4 q0 = *(const uint4*)(zh + (size_t)(s0.x & 0x1FFFFu) * HID + cs);
                uint4 q1 = *(const uint4*)(zh + (size_t)(s1.x & 0x1FFFFu) * HID + cs);
                uint4 q2 = *(const uint4*)(zh + (size_t)(s2.x & 0x1FFFFu) * HID + cs);
                uint4 q3 = *(const uint4*)(zh + (size_t)(s3.x & 0x1FFFFu) * HID + cs);
                acc[0] += lo_f(q0.x) + lo_f(q1.x) + lo_f(q2.x) + lo_f(q3.x);
                acc[1] += hi_f(q0.x) + hi_f(q1.x) + hi_f(q2.x) + hi_f(q3.x);
                acc[2] += lo_f(q0.y) + lo_f(q1.y) + lo_f(q2.y) + lo_f(q3.y);
                acc[3] += hi_f(q0.y) + hi_f(q1.y) + hi_f(q2.y) + hi_f(q3.y);
                acc[4] += lo_f(q0.z) + lo_f(q1.z) + lo_f(q2.z) + lo_f(q3.z);
                acc[5] += hi_f(q0.z) + hi_f(q1.z) + hi_f(q2.z) + hi_f(q3.z);
                acc[6] += lo_f(q0.w) + lo_f(q1.w) + lo_f(q2.w) + lo_f(q3.w);
                acc[7] += hi_f(q0.w) + hi_f(q1.w) + hi_f(q2.w) + hi_f(q3.w);
            }
            for (; k < ke; ++k) {
                uint2 s0 = su[sidx[k]];
                uint4 q0 = *(const uint4*)(zh + (size_t)(s0.x & 0x1FFFFu) * HID + cs);
                acc[0] += lo_f(q0.x); acc[1] += hi_f(q0.x);
                acc[2] += lo_f(q0.y); acc[3] += hi_f(q0.y);
                acc[4] += lo_f(q0.z); acc[5] += hi_f(q0.z);
                acc[6] += lo_f(q0.w); acc[7] += hi_f(q0.w);
            }
            degT += (float)hist[dl];
        }
        __syncthreads();
    }
    // per-node mean path -> facc; self h -> hl
    if (dl < BN) {
        size_t i = (size_t)b * BN + dl;
        float inv = 1.0f / fmaxf(degT, 1.0f);
        float a0 = sa[i * 3 + 0], a1 = sa[i * 3 + 1], a2 = sa[i * 3 + 2];
        float4 f0, f1;
        float* fo = (float*)&f0;
        float* f1o = (float*)&f1;
#pragma unroll
        for (int j = 0; j < 4; ++j) {
            fo[j] = (acc[j] + a0 * swe[cs + j] + a1 * swe[16 + cs + j] +
                     a2 * swe[32 + cs + j] + degT * sbe[cs + j]) * inv;
            f1o[j] = (acc[4 + j] + a0 * swe[cs + 4 + j] + a1 * swe[16 + cs + 4 + j] +
                      a2 * swe[32 + cs + 4 + j] + degT * sbe[cs + 4 + j]) * inv;
        }
        *(float4*)&facc[dl * HID + cs] = f0;
        *(float4*)&facc[dl * HID + cs + 4] = f1;
        *(uint4*)&hl[dl * HID + cs] = *(const uint4*)(zh + i * HID + cs);
    }
    __syncthreads();
    for (int idx = t; idx < BN * OUT_CH; idx += 256) {
        int dli = idx >> 6, j = idx & 63;
        size_t i = (size_t)b * BN + dli;
        float o = sbb[j];
#pragma unroll
        for (int cc = 0; cc < HID; ++cc)
            o += facc[dli * HID + cc] * w2l[cc * OUT_CH + j] +
                 b2f(hl[dli * HID + cc]) * w2r[cc * OUT_CH + j];
        if (bf)
            ((bf16*)out)[i * OUT_CH + j] = __float2bfloat16(o);
        else
            ((float*)out)[i * OUT_CH + j] = o;
    }
}

extern "C" void kernel_launch(void* const* d_in, const int* in_sizes, int n_in,
                              void* d_out, int out_size, void* d_ws, size_t ws_size,
                              hipStream_t stream) {
    const void* x   = d_in[0];
    const int*  ei  = (const int*)d_in[1];
    const void* ea  = d_in[2];
    const void* W1l = d_in[3];
    const void* b1l = d_in[4];
    const void* W1r = d_in[5];
    const void* b1r = d_in[6];
    const void* W1e = d_in[7];
    const void* b1e = d_in[8];
    const void* W2l = d_in[9];
    const void* b2l = d_in[10];
    const void* W2r = d_in[11];
    const void* b2r = d_in[12];
    const void* W2e = d_in[13];
    const void* b2e = d_in[14];

    const size_t N16 = (size_t)N_NODES * HID;
    char* p = (char*)d_ws;
    uint2*    slots  = (uint2*)p;    p += (size_t)N_EDGES * sizeof(uint2);      // 9.6 MB
    uint16_t* ea2v   = (uint16_t*)p; p += (size_t)N_EDGES * sizeof(uint16_t);   // 2.4 MB
    bf16*     y      = (bf16*)p;     p += N16 * sizeof(bf16);                   // 3.2 MB
    bf16*     zh     = (bf16*)p;     p += N16 * sizeof(bf16);                   // 3.2 MB
    float*    sa     = (float*)p;    p += (size_t)3 * N_NODES * sizeof(float);  // 1.2 MB
    int*      bcount = (int*)p;      p += NB * sizeof(int);
    int*      boff   = (int*)p;      p += (NB + 1) * sizeof(int);
    int*      cursor = (int*)p;      p += NB * sizeof(int);
    float*    wc     = (float*)p;    p += 64 * sizeof(float);
    int*      flags  = (int*)p;      p += 2 * sizeof(int);
    // total ~19.6 MB

    hipMemsetAsync(bcount, 0, NB * sizeof(int), stream);

    k_prep<<<1, 64, 0, stream>>>(x, ei, W1e, b1e, W1l, wc, flags);
    k_y<<<((size_t)N_NODES * 32 + 255) / 256, 256, 0, stream>>>(x, W1l, W1r, b1l, b1r,
                                                                flags, y, zh);
    k_bhist<<<128, 256, 0, stream>>>(ei, flags, bcount);
    k_bscan<<<1, 1024, 0, stream>>>(bcount, boff, cursor);
    k_bscatter<<<(N_EDGES + SC_EPB - 1) / SC_EPB, 512, 0, stream>>>(ei, ea, flags, cursor,
                                                                    slots, ea2v);
    k_agg1<<<NB, 256, 0, stream>>>(slots, ea2v, boff, y, wc, zh, sa);
    k_agg2<<<NB, 256, 0, stream>>>(slots, boff, zh, sa, W2l, b2l, W2r, b2r,
                                   W2e, b2e, flags, d_out);
}